// Round 5
// baseline (586.957 us; speedup 1.0000x reference)
//
#include <hip/hip_runtime.h>
#include <stdint.h>

typedef _Float16 half2_t __attribute__((ext_vector_type(2)));
typedef short bf16x8 __attribute__((ext_vector_type(8)));
typedef float f32x4 __attribute__((ext_vector_type(4)));
typedef unsigned short u16;
typedef unsigned int u32;
typedef unsigned long long u64;

#define B_ 64
#define S_ 512
#define D_ 512
#define H_ 512
#define FF_ 1024
#define C_ 1000

// scaling: Wq = round(1024*Wh) i8, g = round(1536*h) i8 in [0,127]
// g_new = relu(1536*xp + (g . Wq)/1024)
#define SW 1024.0f
#define SH 1536.0f

__device__ __forceinline__ u16 f2bf(float f){
  u32 u = __builtin_bit_cast(u32, f);
  u = (u + 0x7FFFu + ((u >> 16) & 1u)) >> 16;
  return (u16)u;
}
__device__ __forceinline__ u32 pkbf(float a, float b){
  return (u32)f2bf(a) | ((u32)f2bf(b) << 16);
}
__device__ __forceinline__ u32 packh2(float a, float b){
  u16 lo = __builtin_bit_cast(u16, (_Float16)a);
  u16 hi = __builtin_bit_cast(u16, (_Float16)b);
  return (u32)lo | ((u32)hi << 16);
}
__device__ __forceinline__ float fdot2u(u32 a, u32 b, float c){
  return __builtin_amdgcn_fdot2(__builtin_bit_cast(half2_t, a),
                                __builtin_bit_cast(half2_t, b), c, false);
}
__device__ __forceinline__ float h2f(u16 h){
  return (float)__builtin_bit_cast(_Float16, h);
}
__device__ __forceinline__ int dot4(u32 a, u32 b, int c){
  return __builtin_amdgcn_sdot4((int)a, (int)b, c, false);
}

// ---- P2: transpose+convert Wx [512k][512n] f32 -> WxT [512n][512k] bf16 ----
__global__ void k_trans_cvt(const float* __restrict__ src, u16* __restrict__ dst){
  __shared__ u16 t[64][65];
  int bx = blockIdx.x & 7, by = blockIdx.x >> 3;
  int tid = threadIdx.x;
  int c = tid & 63, r0 = (tid >> 6) * 16;
  #pragma unroll
  for (int i = 0; i < 16; i++){
    int k = by * 64 + r0 + i, n = bx * 64 + c;
    t[r0 + i][c] = f2bf(src[k * 512 + n]);
  }
  __syncthreads();
  #pragma unroll
  for (int i = 0; i < 16; i++){
    int n = bx * 64 + r0 + i, k = by * 64 + c;
    dst[n * 512 + k] = t[c][r0 + i];
  }
}

// ---- P3: Wh f32 -> i8 (x1024), column-major dword-packed for dot4 ----
// Wd[c*512 + col] = uint4 of dwords dw=0..3, dword packs Wh[16c+4dw+j][col], j=0..3
__global__ void k_prep_wdot(const float* __restrict__ Wh, uint4* __restrict__ Wd){
  int g = blockIdx.x * 256 + threadIdx.x;      // 16384 = 32 chunks x 512 cols
  int c = g >> 9, col = g & 511;
  u32 d[4];
  #pragma unroll
  for (int dw = 0; dw < 4; dw++){
    u32 acc = 0;
    #pragma unroll
    for (int j = 0; j < 4; j++){
      float w = Wh[(size_t)(c * 16 + dw * 4 + j) * 512 + col] * SW;
      int q = (int)fminf(fmaxf(rintf(w), -127.f), 127.f);
      acc |= ((u32)(q & 0xFF)) << (8 * j);
    }
    d[dw] = acc;
  }
  uint4 o; o.x = d[0]; o.y = d[1]; o.z = d[2]; o.w = d[3];
  Wd[(size_t)c * 512 + col] = o;
}

// ---- P5: token mask -> byte per step ----
__global__ void k_mask(const int* __restrict__ tokens, unsigned char* __restrict__ masks8){
  int i = blockIdx.x * 256 + threadIdx.x;       // 32768
  masks8[i] = (tokens[i] != 0) ? 1 : 0;
}

// ---- P4: generic pack K-pairs: dst[p*N+n] = half2(src[2p][n], src[2p+1][n]) ----
__global__ void k_pack_pairs(const float* __restrict__ src, u32* __restrict__ dst, int N){
  int n = blockIdx.x * 256 + threadIdx.x;
  int p = blockIdx.y;
  if (n >= N) return;
  dst[p * N + n] = packh2(src[(2 * p) * N + n], src[(2 * p + 1) * N + n]);
}

// ---- G1: xproj = SH*(gather(emb,tok) @ Wx + b_rnn), fused gather+convert ----
__global__ __launch_bounds__(256) void k_gemm(const int* __restrict__ tokens,
                                              const float* __restrict__ emb,
                                              const u16* __restrict__ Bt,
                                              const float* __restrict__ bias,
                                              u16* __restrict__ out){
  __shared__ __align__(16) u16 As[128 * 40];
  __shared__ __align__(16) u16 Bs[128 * 40];
  int tid = threadIdx.x;
  int m0 = blockIdx.x * 128, n0 = blockIdx.y * 128;
  int w = tid >> 6, l = tid & 63;
  int wr = w >> 1, wc = w & 1;
  int kg = l >> 4, r16 = l & 15;
  f32x4 acc[4][4];
  #pragma unroll
  for (int mi = 0; mi < 4; mi++)
    #pragma unroll
    for (int ni = 0; ni < 4; ni++) acc[mi][ni] = (f32x4){0.f, 0.f, 0.f, 0.f};
  int srow = tid >> 1, spart = tid & 1;
  int tk = tokens[m0 + srow];                   // gather row: one token per A-row
  for (int kt = 0; kt < 512; kt += 32){
    const float4* se = (const float4*)(emb + (size_t)tk * 512 + kt + spart * 16);
    float4 f0 = se[0], f1 = se[1], f2 = se[2], f3 = se[3];
    uint4 a0, a1;
    a0.x = pkbf(f0.x, f0.y); a0.y = pkbf(f0.z, f0.w);
    a0.z = pkbf(f1.x, f1.y); a0.w = pkbf(f1.z, f1.w);
    a1.x = pkbf(f2.x, f2.y); a1.y = pkbf(f2.z, f2.w);
    a1.z = pkbf(f3.x, f3.y); a1.w = pkbf(f3.z, f3.w);
    const uint4* sb = (const uint4*)(Bt + (size_t)(n0 + srow) * 512 + kt);
    uint4 b0 = sb[spart * 2], b1 = sb[spart * 2 + 1];
    uint4* da = (uint4*)(As + srow * 40 + spart * 16);
    da[0] = a0; da[1] = a1;
    uint4* db = (uint4*)(Bs + srow * 40 + spart * 16);
    db[0] = b0; db[1] = b1;
    __syncthreads();
    bf16x8 af[4], bfr[4];
    #pragma unroll
    for (int mi = 0; mi < 4; mi++)
      af[mi] = *(const bf16x8*)(As + (wr * 64 + mi * 16 + r16) * 40 + kg * 8);
    #pragma unroll
    for (int ni = 0; ni < 4; ni++)
      bfr[ni] = *(const bf16x8*)(Bs + (wc * 64 + ni * 16 + r16) * 40 + kg * 8);
    #pragma unroll
    for (int mi = 0; mi < 4; mi++)
      #pragma unroll
      for (int ni = 0; ni < 4; ni++)
        acc[mi][ni] = __builtin_amdgcn_mfma_f32_16x16x32_bf16(af[mi], bfr[ni], acc[mi][ni], 0, 0, 0);
    __syncthreads();
  }
  #pragma unroll
  for (int ni = 0; ni < 4; ni++){
    int col = n0 + wc * 64 + ni * 16 + r16;
    float bb = bias[col];
    #pragma unroll
    for (int mi = 0; mi < 4; mi++){
      int mb = m0 + wr * 64 + mi * 16 + kg * 4;
      #pragma unroll
      for (int r = 0; r < 4; r++){
        float v = (acc[mi][ni][r] + bb) * SH;
        out[(size_t)(mb + r) * 512 + col] = __builtin_bit_cast(u16, (_Float16)v);
      }
    }
  }
}

// ---- R: 512-step RNN scan via VALU i8 dot4. 64 blocks x 512 thr (8 waves). ----
// One column per thread; the column's 512 i8 weights in 128 VGPRs (w4[32],
// statically indexed). h (i8, x1536) double-buffered in LDS; broadcast b128
// reads. No replication waste: 1024 useful OP/cy/CU vs MFMA's 400.
__global__ __launch_bounds__(512, 2) void k_rnn(
    const uint4* __restrict__ Wd, const u16* __restrict__ xproj,
    const unsigned char* __restrict__ masks8, u32* __restrict__ hpack){
  __shared__ __align__(16) unsigned char g8[2][512];
  __shared__ unsigned char msk[512];
  int b = blockIdx.x, tid = threadIdx.x;

  uint4 w4[32];
  #pragma unroll
  for (int c = 0; c < 32; c++) w4[c] = Wd[(size_t)c * 512 + tid];

  msk[tid] = masks8[b * 512 + tid];
  if (tid < 128) ((u32*)g8[0])[tid] = 0;
  __syncthreads();

  const u16* xp = xproj + (size_t)b * S_ * H_;
  float xpf = h2f(xp[tid]);
  u32 greg = 0;

  #pragma unroll 2
  for (int t = 0; t < 512; t++){
    u16 xn = 0;
    if (t < 511) xn = xp[(size_t)(t + 1) * 512 + tid];   // issued early, used late
    const unsigned char* gc = g8[t & 1];
    int acc0 = 0, acc1 = 0;
    #pragma unroll
    for (int c = 0; c < 32; c += 2){
      uint4 h0 = *(const uint4*)(gc + c * 16);
      uint4 h1 = *(const uint4*)(gc + c * 16 + 16);
      acc0 = dot4(h0.x, w4[c].x, acc0);
      acc0 = dot4(h0.y, w4[c].y, acc0);
      acc0 = dot4(h0.z, w4[c].z, acc0);
      acc0 = dot4(h0.w, w4[c].w, acc0);
      acc1 = dot4(h1.x, w4[c + 1].x, acc1);
      acc1 = dot4(h1.y, w4[c + 1].y, acc1);
      acc1 = dot4(h1.z, w4[c + 1].z, acc1);
      acc1 = dot4(h1.w, w4[c + 1].w, acc1);
    }
    float gn = fmaxf(fmaf((float)(acc0 + acc1), 1.0f / SW, xpf), 0.f);
    u32 q8 = (u32)(int)fminf(rintf(gn), 127.f);
    if (msk[t]) greg = q8;
    g8[(t + 1) & 1][tid] = (unsigned char)greg;
    xpf = h2f(xn);
    __syncthreads();
  }

  if (tid < 256){
    float f0 = (float)g8[0][2 * tid] * (1.0f / SH);
    float f1 = (float)g8[0][2 * tid + 1] * (1.0f / SH);
    hpack[b * 256 + tid] = packh2(f0, f1);
  }
}

// ---- H1: y1 = relu(h @ W1 + b1), packed output ----
__global__ __launch_bounds__(256) void k_fc1(const u32* __restrict__ hpack, const u32* __restrict__ W1p,
                                             const float* __restrict__ b1, u32* __restrict__ y1p){
  __shared__ u32 hrow[256];
  int b = blockIdx.y, tid = threadIdx.x;
  int n = blockIdx.x * 256 + tid;
  hrow[tid] = hpack[b * 256 + tid];
  __syncthreads();
  float a0 = 0.f, a1 = 0.f;
  #pragma unroll 8
  for (int p = 0; p < 256; p += 2){
    a0 = fdot2u(W1p[p * FF_ + n], hrow[p], a0);
    a1 = fdot2u(W1p[(p + 1) * FF_ + n], hrow[p + 1], a1);
  }
  float acc = fmaxf(a0 + a1 + b1[n], 0.f);
  float other = __shfl_xor(acc, 1);
  if ((tid & 1) == 0) y1p[b * 512 + (n >> 1)] = packh2(acc, other);
}

// ---- H2: y2 = relu(y1 @ W2 + b2), packed output ----
__global__ __launch_bounds__(256) void k_fc2(const u32* __restrict__ y1p, const u32* __restrict__ W2p,
                                             const float* __restrict__ b2, u32* __restrict__ y2p){
  __shared__ u32 yrow[512];
  int b = blockIdx.y, tid = threadIdx.x;
  int n = blockIdx.x * 256 + tid;
  yrow[tid] = y1p[b * 512 + tid];
  yrow[tid + 256] = y1p[b * 512 + 256 + tid];
  __syncthreads();
  float a0 = 0.f, a1 = 0.f;
  #pragma unroll 8
  for (int p = 0; p < 512; p += 2){
    a0 = fdot2u(W2p[p * FF_ + n], yrow[p], a0);
    a1 = fdot2u(W2p[(p + 1) * FF_ + n], yrow[p + 1], a1);
  }
  float acc = fmaxf(a0 + a1 + b2[n], 0.f);
  float other = __shfl_xor(acc, 1);
  if ((tid & 1) == 0) y2p[b * 512 + (n >> 1)] = packh2(acc, other);
}

// ---- H3: z = y2 @ Wo + bo, softmax, write f32 output [64][1000] ----
__global__ __launch_bounds__(256) void k_out(const u32* __restrict__ y2p, const u32* __restrict__ Wop,
                                             const float* __restrict__ bo, float* __restrict__ out){
  __shared__ u32 yrow[512];
  __shared__ float redm[4], reds[4];
  int b = blockIdx.x, tid = threadIdx.x;
  yrow[tid] = y2p[b * 512 + tid];
  yrow[tid + 256] = y2p[b * 512 + 256 + tid];
  __syncthreads();
  int n0 = tid, n1 = tid + 256, n2 = tid + 512, n3 = tid + 768;
  bool v3 = n3 < C_;
  int n3c = v3 ? n3 : 0;
  float z0 = 0.f, z1 = 0.f, z2 = 0.f, z3 = 0.f;
  #pragma unroll 4
  for (int p = 0; p < 512; p++){
    u32 y = yrow[p];
    z0 = fdot2u(Wop[p * C_ + n0], y, z0);
    z1 = fdot2u(Wop[p * C_ + n1], y, z1);
    z2 = fdot2u(Wop[p * C_ + n2], y, z2);
    z3 = fdot2u(Wop[p * C_ + n3c], y, z3);
  }
  z0 += bo[n0]; z1 += bo[n1]; z2 += bo[n2]; z3 += bo[n3c];
  float mx = fmaxf(fmaxf(z0, z1), z2);
  if (v3) mx = fmaxf(mx, z3);
  #pragma unroll
  for (int o = 1; o < 64; o <<= 1) mx = fmaxf(mx, __shfl_xor(mx, o));
  if ((tid & 63) == 0) redm[tid >> 6] = mx;
  __syncthreads();
  mx = fmaxf(fmaxf(redm[0], redm[1]), fmaxf(redm[2], redm[3]));
  float e0 = __expf(z0 - mx), e1 = __expf(z1 - mx), e2 = __expf(z2 - mx);
  float e3 = v3 ? __expf(z3 - mx) : 0.f;
  float s = e0 + e1 + e2 + e3;
  #pragma unroll
  for (int o = 1; o < 64; o <<= 1) s += __shfl_xor(s, o);
  if ((tid & 63) == 0) reds[tid >> 6] = s;
  __syncthreads();
  s = reds[0] + reds[1] + reds[2] + reds[3];
  float inv = 1.0f / s;
  out[b * C_ + n0] = e0 * inv;
  out[b * C_ + n1] = e1 * inv;
  out[b * C_ + n2] = e2 * inv;
  if (v3) out[b * C_ + n3] = e3 * inv;
}

extern "C" void kernel_launch(void* const* d_in, const int* in_sizes, int n_in,
                              void* d_out, int out_size, void* d_ws, size_t ws_size,
                              hipStream_t stream) {
  const int*   tokens = (const int*)d_in[0];
  const float* emb    = (const float*)d_in[1];
  const float* Wx     = (const float*)d_in[2];
  const float* Wh     = (const float*)d_in[3];
  const float* brnn   = (const float*)d_in[4];
  const float* W1     = (const float*)d_in[5];
  const float* b1     = (const float*)d_in[6];
  const float* W2     = (const float*)d_in[7];
  const float* b2     = (const float*)d_in[8];
  const float* Wo     = (const float*)d_in[9];
  const float* bo     = (const float*)d_in[10];
  float* out = (float*)d_out;

  char* ws = (char*)d_ws;
  size_t off = 0;
  auto alloc = [&](size_t bytes) -> void* {
    void* p = ws + off;
    off += (bytes + 255) & ~(size_t)255;
    return p;
  };
  u16* WxT    = (u16*)alloc((size_t)512 * 512 * 2);     // Wx transposed, bf16
  u16* xproj  = (u16*)alloc((size_t)32768 * 512 * 2);   // SH*(x@Wx + b), f16
  uint4* Wd   = (uint4*)alloc((size_t)32 * 512 * 16);   // Wh i8 dot4 layout
  unsigned char* masks8 = (unsigned char*)alloc(32768); // token!=0 bytes
  u32* W1p    = (u32*)alloc((size_t)256 * 1024 * 4);
  u32* W2p    = (u32*)alloc((size_t)512 * 1024 * 4);
  u32* Wop    = (u32*)alloc((size_t)512 * 1000 * 4);
  u32* hpack  = (u32*)alloc((size_t)64 * 256 * 4);
  u32* y1p    = (u32*)alloc((size_t)64 * 512 * 4);
  u32* y2p    = (u32*)alloc((size_t)64 * 512 * 4);

  k_trans_cvt<<<dim3(64), dim3(256), 0, stream>>>(Wx, WxT);
  k_prep_wdot<<<dim3(64), dim3(256), 0, stream>>>(Wh, Wd);
  k_mask<<<dim3(128), dim3(256), 0, stream>>>(tokens, masks8);
  k_pack_pairs<<<dim3(4, 256), dim3(256), 0, stream>>>(W1, W1p, 1024);
  k_pack_pairs<<<dim3(4, 512), dim3(256), 0, stream>>>(W2, W2p, 1024);
  k_pack_pairs<<<dim3(4, 512), dim3(256), 0, stream>>>(Wo, Wop, 1000);
  k_gemm<<<dim3(256, 4), dim3(256), 0, stream>>>(tokens, emb, WxT, brnn, xproj);
  k_rnn<<<dim3(64), dim3(512), 0, stream>>>(Wd, xproj, masks8, hpack);
  k_fc1<<<dim3(4, 64), dim3(256), 0, stream>>>(hpack, W1p, b1, y1p);
  k_fc2<<<dim3(4, 64), dim3(256), 0, stream>>>(y1p, W2p, b2, y2p);
  k_out<<<dim3(64), dim3(256), 0, stream>>>(y2p, Wop, bo, out);
}

// Round 6
// 421.717 us; speedup vs baseline: 1.3918x; 1.3918x over previous
//
#include <hip/hip_runtime.h>
#include <stdint.h>

typedef _Float16 half2_t __attribute__((ext_vector_type(2)));
typedef short bf16x8 __attribute__((ext_vector_type(8)));
typedef float f32x4 __attribute__((ext_vector_type(4)));
typedef int i32x4 __attribute__((ext_vector_type(4)));
typedef int i32x8 __attribute__((ext_vector_type(8)));
typedef unsigned short u16;
typedef unsigned int u32;
typedef unsigned long long u64;

#define B_ 64
#define S_ 512
#define D_ 512
#define H_ 512
#define FF_ 1024
#define C_ 1000

// scaling: W' = 128*Wh (fp4 e2m1), g = 256*h (fp4, >=0).
// g_new = relu(256*xp + (g . W')/128)
#define SW4 128.0f
#define SH4 256.0f

__device__ __forceinline__ u16 f2bf(float f){
  u32 u = __builtin_bit_cast(u32, f);
  u = (u + 0x7FFFu + ((u >> 16) & 1u)) >> 16;
  return (u16)u;
}
__device__ __forceinline__ u32 pkbf(float a, float b){
  return (u32)f2bf(a) | ((u32)f2bf(b) << 16);
}
__device__ __forceinline__ u32 packh2(float a, float b){
  u16 lo = __builtin_bit_cast(u16, (_Float16)a);
  u16 hi = __builtin_bit_cast(u16, (_Float16)b);
  return (u32)lo | ((u32)hi << 16);
}
__device__ __forceinline__ float fdot2u(u32 a, u32 b, float c){
  return __builtin_amdgcn_fdot2(__builtin_bit_cast(half2_t, a),
                                __builtin_bit_cast(half2_t, b), c, false);
}
__device__ __forceinline__ float h2f(u16 h){
  return (float)__builtin_bit_cast(_Float16, h);
}
// decode fp4 e2m1 magnitude code (0..7) -> value {0,.5,1,1.5,2,3,4,6}
__device__ __forceinline__ float fp4val(u32 c){
  int e = (c >> 1) & 3;
  float m = 1.0f + 0.5f * (float)(c & 1);
  return (e == 0) ? 0.5f * (float)(c & 1) : m * (float)(1 << (e - 1));
}

// ---- P2: transpose+convert Wx [512k][512n] f32 -> WxT [512n][512k] bf16 ----
__global__ void k_trans_cvt(const float* __restrict__ src, u16* __restrict__ dst){
  __shared__ u16 t[64][65];
  int bx = blockIdx.x & 7, by = blockIdx.x >> 3;
  int tid = threadIdx.x;
  int c = tid & 63, r0 = (tid >> 6) * 16;
  #pragma unroll
  for (int i = 0; i < 16; i++){
    int k = by * 64 + r0 + i, n = bx * 64 + c;
    t[r0 + i][c] = f2bf(src[k * 512 + n]);
  }
  __syncthreads();
  #pragma unroll
  for (int i = 0; i < 16; i++){
    int n = bx * 64 + r0 + i, k = by * 64 + c;
    dst[n * 512 + k] = t[c][r0 + i];
  }
}

// ---- P3: Wh f32 -> fp4 e2m1 (x128) B-fragments for mfma 16x16x128 f8f6f4 ----
// frag fidx = (wv*4+ct)*4+kt; lane l holds B[k][n]: n = 64wv+16ct+(l&15),
// k = 128kt + 32q + j (q=l>>4, j=0..31), nibble j at bits 4(j&7) of dword j>>3.
__global__ void k_prep_w4(const float* __restrict__ Wh, uint4* __restrict__ Wf4){
  int g = blockIdx.x * 256 + threadIdx.x;      // 8192 = 128 frags x 64 lanes
  int fidx = g >> 6, l = g & 63;
  int wv = fidx >> 4, ct = (fidx >> 2) & 3, kt = fidx & 3;
  int q = l >> 4, n = wv * 64 + ct * 16 + (l & 15);
  int k0 = kt * 128 + q * 32;
  u32 d[4] = {0u, 0u, 0u, 0u};
  #pragma unroll
  for (int j = 0; j < 32; j++){
    float w = Wh[(size_t)(k0 + j) * 512 + n] * SW4;
    float aw = fabsf(w);
    u32 s = (w < 0.f) ? 8u : 0u;
    u32 c;
    if (aw < 2.f) c = (u32)(int)rintf(aw * 2.f);
    else if (aw < 4.f) c = 4u + (u32)(int)rintf(aw - 2.f);
    else { c = 6u + (u32)(int)rintf((aw - 4.f) * 0.5f); if (c > 7u) c = 7u; }
    d[j >> 3] |= (c | s) << (4 * (j & 7));
  }
  uint4 o; o.x = d[0]; o.y = d[1]; o.z = d[2]; o.w = d[3];
  Wf4[(size_t)fidx * 64 + l] = o;
}

// ---- P5: token mask -> byte per step ----
__global__ void k_mask(const int* __restrict__ tokens, unsigned char* __restrict__ masks8){
  int i = blockIdx.x * 256 + threadIdx.x;       // 32768
  masks8[i] = (tokens[i] != 0) ? 1 : 0;
}

// ---- P4: generic pack K-pairs: dst[p*N+n] = half2(src[2p][n], src[2p+1][n]) ----
__global__ void k_pack_pairs(const float* __restrict__ src, u32* __restrict__ dst, int N){
  int n = blockIdx.x * 256 + threadIdx.x;
  int p = blockIdx.y;
  if (n >= N) return;
  dst[p * N + n] = packh2(src[(2 * p) * N + n], src[(2 * p + 1) * N + n]);
}

// ---- G1: xproj = SH4*(gather(emb,tok) @ Wx + b_rnn), fused gather, f16 out ----
__global__ __launch_bounds__(256) void k_gemm(const int* __restrict__ tokens,
                                              const float* __restrict__ emb,
                                              const u16* __restrict__ Bt,
                                              const float* __restrict__ bias,
                                              u16* __restrict__ out){
  __shared__ __align__(16) u16 As[128 * 40];
  __shared__ __align__(16) u16 Bs[128 * 40];
  int tid = threadIdx.x;
  int m0 = blockIdx.x * 128, n0 = blockIdx.y * 128;
  int w = tid >> 6, l = tid & 63;
  int wr = w >> 1, wc = w & 1;
  int kg = l >> 4, r16 = l & 15;
  f32x4 acc[4][4];
  #pragma unroll
  for (int mi = 0; mi < 4; mi++)
    #pragma unroll
    for (int ni = 0; ni < 4; ni++) acc[mi][ni] = (f32x4){0.f, 0.f, 0.f, 0.f};
  int srow = tid >> 1, spart = tid & 1;
  int tk = tokens[m0 + srow];
  for (int kt = 0; kt < 512; kt += 32){
    const float4* se = (const float4*)(emb + (size_t)tk * 512 + kt + spart * 16);
    float4 f0 = se[0], f1 = se[1], f2 = se[2], f3 = se[3];
    uint4 a0, a1;
    a0.x = pkbf(f0.x, f0.y); a0.y = pkbf(f0.z, f0.w);
    a0.z = pkbf(f1.x, f1.y); a0.w = pkbf(f1.z, f1.w);
    a1.x = pkbf(f2.x, f2.y); a1.y = pkbf(f2.z, f2.w);
    a1.z = pkbf(f3.x, f3.y); a1.w = pkbf(f3.z, f3.w);
    const uint4* sb = (const uint4*)(Bt + (size_t)(n0 + srow) * 512 + kt);
    uint4 b0 = sb[spart * 2], b1 = sb[spart * 2 + 1];
    uint4* da = (uint4*)(As + srow * 40 + spart * 16);
    da[0] = a0; da[1] = a1;
    uint4* db = (uint4*)(Bs + srow * 40 + spart * 16);
    db[0] = b0; db[1] = b1;
    __syncthreads();
    bf16x8 af[4], bfr[4];
    #pragma unroll
    for (int mi = 0; mi < 4; mi++)
      af[mi] = *(const bf16x8*)(As + (wr * 64 + mi * 16 + r16) * 40 + kg * 8);
    #pragma unroll
    for (int ni = 0; ni < 4; ni++)
      bfr[ni] = *(const bf16x8*)(Bs + (wc * 64 + ni * 16 + r16) * 40 + kg * 8);
    #pragma unroll
    for (int mi = 0; mi < 4; mi++)
      #pragma unroll
      for (int ni = 0; ni < 4; ni++)
        acc[mi][ni] = __builtin_amdgcn_mfma_f32_16x16x32_bf16(af[mi], bfr[ni], acc[mi][ni], 0, 0, 0);
    __syncthreads();
  }
  #pragma unroll
  for (int ni = 0; ni < 4; ni++){
    int col = n0 + wc * 64 + ni * 16 + r16;
    float bb = bias[col];
    #pragma unroll
    for (int mi = 0; mi < 4; mi++){
      int mb = m0 + wr * 64 + mi * 16 + kg * 4;
      #pragma unroll
      for (int r = 0; r < 4; r++){
        float v = (acc[mi][ni][r] + bb) * SH4;
        out[(size_t)(mb + r) * 512 + col] = __builtin_bit_cast(u16, (_Float16)v);
      }
    }
  }
}

// ---- R: 512-step RNN scan via MX-fp4 MFMA (K=128). 64 blocks x 512 thr. ----
// A = h replicated over M (fp4 nibbles in LDS, 16B/lane/ktile); B = weights
// (fp4 fragments, register/AGPR-resident). Lane owns col = 64wv+16q+(l&15);
// after MFMA its value is acc[q][0]. Nibble-pair pack via shfl_xor(1).
__global__ __launch_bounds__(512, 2) void k_rnn(
    const uint4* __restrict__ Wf4, const u16* __restrict__ xproj,
    const unsigned char* __restrict__ masks8, u32* __restrict__ hpack){
  __shared__ __align__(16) unsigned char g4[2][256];
  __shared__ unsigned char msk[512];
  int b = blockIdx.x, tid = threadIdx.x;
  int wv = tid >> 6, l = tid & 63, q = l >> 4, n16 = l & 15;
  int col = wv * 64 + q * 16 + n16;

  i32x8 wgt[16];
  #pragma unroll
  for (int ct = 0; ct < 4; ct++)
    #pragma unroll
    for (int kt = 0; kt < 4; kt++){
      int fidx = (wv * 4 + ct) * 4 + kt;
      uint4 wl = Wf4[(size_t)fidx * 64 + l];
      i32x8 w8 = {(int)wl.x, (int)wl.y, (int)wl.z, (int)wl.w, 0, 0, 0, 0};
      wgt[ct * 4 + kt] = w8;
    }

  msk[tid] = masks8[b * 512 + tid];
  if (tid < 64) ((u32*)g4[0])[tid] = 0;
  __syncthreads();

  const u16* xp = xproj + (size_t)b * S_ * H_;
  u16 xraw = xp[col];
  u32 greg = 0;

  #pragma unroll 1
  for (int t = 0; t < 512; t++){
    u16 xnext = 0;
    if (t < 511) xnext = xp[(size_t)(t + 1) * 512 + col];   // prefetch
    bool wr = msk[t] != 0;
    const unsigned char* gc = g4[t & 1];

    f32x4 acc0 = {0.f,0.f,0.f,0.f}, acc1 = {0.f,0.f,0.f,0.f};
    f32x4 acc2 = {0.f,0.f,0.f,0.f}, acc3 = {0.f,0.f,0.f,0.f};
    #pragma unroll
    for (int kt = 0; kt < 4; kt++){
      i32x4 av = *(const i32x4*)(gc + kt * 64 + q * 16);
      i32x8 a8 = {av[0], av[1], av[2], av[3], 0, 0, 0, 0};
      acc0 = __builtin_amdgcn_mfma_scale_f32_16x16x128_f8f6f4(
          a8, wgt[0 * 4 + kt], acc0, 4, 4, 0, 127, 0, 127);
      acc1 = __builtin_amdgcn_mfma_scale_f32_16x16x128_f8f6f4(
          a8, wgt[1 * 4 + kt], acc1, 4, 4, 0, 127, 0, 127);
      acc2 = __builtin_amdgcn_mfma_scale_f32_16x16x128_f8f6f4(
          a8, wgt[2 * 4 + kt], acc2, 4, 4, 0, 127, 0, 127);
      acc3 = __builtin_amdgcn_mfma_scale_f32_16x16x128_f8f6f4(
          a8, wgt[3 * 4 + kt], acc3, 4, 4, 0, 127, 0, 127);
    }

    float av = (q == 0) ? acc0[0] : (q == 1) ? acc1[0] : (q == 2) ? acc2[0] : acc3[0];
    float gn = fmaxf(fmaf(av, 1.0f / SW4, h2f(xraw)), 0.f);
    u32 code;
    if (gn < 2.f) code = (u32)(int)rintf(gn * 2.f);
    else if (gn < 4.f) code = 4u + (u32)(int)rintf(gn - 2.f);
    else { u32 c = 6u + (u32)(int)rintf((gn - 4.f) * 0.5f); code = c > 7u ? 7u : c; }
    u32 pc = (u32)__shfl_xor((int)code, 1);
    u32 byte = (n16 & 1) ? (pc | (code << 4)) : (code | (pc << 4));
    if (wr) greg = byte;
    if ((l & 1) == 0) g4[(t + 1) & 1][col >> 1] = (unsigned char)greg;
    xraw = xnext;
    __syncthreads();
  }

  if (tid < 256){
    u32 byte = g4[0][tid];
    float f0 = fp4val(byte & 15u) * (1.0f / SH4);
    float f1 = fp4val(byte >> 4) * (1.0f / SH4);
    hpack[b * 256 + tid] = packh2(f0, f1);
  }
}

// ---- T: fused fc1+fc2+out+softmax. 64 blocks (1/batch) x 256 threads. ----
__global__ __launch_bounds__(256) void k_tail(const u32* __restrict__ hpack,
    const u32* __restrict__ W1p, const float* __restrict__ b1,
    const u32* __restrict__ W2p, const float* __restrict__ b2,
    const u32* __restrict__ Wop, const float* __restrict__ bo,
    float* __restrict__ out){
  __shared__ __align__(16) u32 rowA[512];
  __shared__ __align__(16) u32 rowB[512];
  __shared__ float redm[4], reds[4];
  int b = blockIdx.x, tid = threadIdx.x;
  rowA[tid] = hpack[b * 256 + tid];
  __syncthreads();

  // fc1: outs n = tid + 256*i, i=0..3; K=256 pairs from rowA[0..255]
  float s0 = 0.f, s1 = 0.f, s2 = 0.f, s3 = 0.f;
  #pragma unroll 2
  for (int p = 0; p < 256; p += 4){
    uint4 h4 = *(const uint4*)&rowA[p];
    const u32* wp = W1p + (size_t)p * FF_ + tid;
    s0 = fdot2u(wp[0], h4.x, s0); s1 = fdot2u(wp[256], h4.x, s1);
    s2 = fdot2u(wp[512], h4.x, s2); s3 = fdot2u(wp[768], h4.x, s3);
    s0 = fdot2u(wp[FF_ + 0], h4.y, s0); s1 = fdot2u(wp[FF_ + 256], h4.y, s1);
    s2 = fdot2u(wp[FF_ + 512], h4.y, s2); s3 = fdot2u(wp[FF_ + 768], h4.y, s3);
    s0 = fdot2u(wp[2*FF_ + 0], h4.z, s0); s1 = fdot2u(wp[2*FF_ + 256], h4.z, s1);
    s2 = fdot2u(wp[2*FF_ + 512], h4.z, s2); s3 = fdot2u(wp[2*FF_ + 768], h4.z, s3);
    s0 = fdot2u(wp[3*FF_ + 0], h4.w, s0); s1 = fdot2u(wp[3*FF_ + 256], h4.w, s1);
    s2 = fdot2u(wp[3*FF_ + 512], h4.w, s2); s3 = fdot2u(wp[3*FF_ + 768], h4.w, s3);
  }
  {
    float y0 = fmaxf(s0 + b1[tid], 0.f);
    float y1 = fmaxf(s1 + b1[tid + 256], 0.f);
    float y2 = fmaxf(s2 + b1[tid + 512], 0.f);
    float y3 = fmaxf(s3 + b1[tid + 768], 0.f);
    float o0 = __shfl_xor(y0, 1), o1 = __shfl_xor(y1, 1);
    float o2 = __shfl_xor(y2, 1), o3 = __shfl_xor(y3, 1);
    if ((tid & 1) == 0){
      int i = tid >> 1;
      rowB[i] = packh2(y0, o0); rowB[128 + i] = packh2(y1, o1);
      rowB[256 + i] = packh2(y2, o2); rowB[384 + i] = packh2(y3, o3);
    }
  }
  __syncthreads();

  // fc2: K=512 pairs from rowB
  s0 = s1 = s2 = s3 = 0.f;
  #pragma unroll 2
  for (int p = 0; p < 512; p += 4){
    uint4 h4 = *(const uint4*)&rowB[p];
    const u32* wp = W2p + (size_t)p * FF_ + tid;
    s0 = fdot2u(wp[0], h4.x, s0); s1 = fdot2u(wp[256], h4.x, s1);
    s2 = fdot2u(wp[512], h4.x, s2); s3 = fdot2u(wp[768], h4.x, s3);
    s0 = fdot2u(wp[FF_ + 0], h4.y, s0); s1 = fdot2u(wp[FF_ + 256], h4.y, s1);
    s2 = fdot2u(wp[FF_ + 512], h4.y, s2); s3 = fdot2u(wp[FF_ + 768], h4.y, s3);
    s0 = fdot2u(wp[2*FF_ + 0], h4.z, s0); s1 = fdot2u(wp[2*FF_ + 256], h4.z, s1);
    s2 = fdot2u(wp[2*FF_ + 512], h4.z, s2); s3 = fdot2u(wp[2*FF_ + 768], h4.z, s3);
    s0 = fdot2u(wp[3*FF_ + 0], h4.w, s0); s1 = fdot2u(wp[3*FF_ + 256], h4.w, s1);
    s2 = fdot2u(wp[3*FF_ + 512], h4.w, s2); s3 = fdot2u(wp[3*FF_ + 768], h4.w, s3);
  }
  {
    float y0 = fmaxf(s0 + b2[tid], 0.f);
    float y1 = fmaxf(s1 + b2[tid + 256], 0.f);
    float y2 = fmaxf(s2 + b2[tid + 512], 0.f);
    float y3 = fmaxf(s3 + b2[tid + 768], 0.f);
    float o0 = __shfl_xor(y0, 1), o1 = __shfl_xor(y1, 1);
    float o2 = __shfl_xor(y2, 1), o3 = __shfl_xor(y3, 1);
    if ((tid & 1) == 0){
      int i = tid >> 1;
      rowA[i] = packh2(y0, o0); rowA[128 + i] = packh2(y1, o1);
      rowA[256 + i] = packh2(y2, o2); rowA[384 + i] = packh2(y3, o3);
    }
  }
  __syncthreads();

  // out: z = y2 @ Wo + bo, softmax over C=1000
  int n0 = tid, n1 = tid + 256, n2 = tid + 512, n3 = tid + 768;
  bool v3 = n3 < C_;
  int n3c = v3 ? n3 : 0;
  float z0 = 0.f, z1 = 0.f, z2 = 0.f, z3 = 0.f;
  #pragma unroll 4
  for (int p = 0; p < 512; p++){
    u32 y = rowA[p];
    z0 = fdot2u(Wop[p * C_ + n0], y, z0);
    z1 = fdot2u(Wop[p * C_ + n1], y, z1);
    z2 = fdot2u(Wop[p * C_ + n2], y, z2);
    z3 = fdot2u(Wop[p * C_ + n3c], y, z3);
  }
  z0 += bo[n0]; z1 += bo[n1]; z2 += bo[n2]; z3 += bo[n3c];
  float mx = fmaxf(fmaxf(z0, z1), z2);
  if (v3) mx = fmaxf(mx, z3);
  #pragma unroll
  for (int o = 1; o < 64; o <<= 1) mx = fmaxf(mx, __shfl_xor(mx, o));
  if ((tid & 63) == 0) redm[tid >> 6] = mx;
  __syncthreads();
  mx = fmaxf(fmaxf(redm[0], redm[1]), fmaxf(redm[2], redm[3]));
  float e0 = __expf(z0 - mx), e1 = __expf(z1 - mx), e2 = __expf(z2 - mx);
  float e3 = v3 ? __expf(z3 - mx) : 0.f;
  float s = e0 + e1 + e2 + e3;
  #pragma unroll
  for (int o = 1; o < 64; o <<= 1) s += __shfl_xor(s, o);
  if ((tid & 63) == 0) reds[tid >> 6] = s;
  __syncthreads();
  s = reds[0] + reds[1] + reds[2] + reds[3];
  float inv = 1.0f / s;
  out[b * C_ + n0] = e0 * inv;
  out[b * C_ + n1] = e1 * inv;
  out[b * C_ + n2] = e2 * inv;
  if (v3) out[b * C_ + n3] = e3 * inv;
}

extern "C" void kernel_launch(void* const* d_in, const int* in_sizes, int n_in,
                              void* d_out, int out_size, void* d_ws, size_t ws_size,
                              hipStream_t stream) {
  const int*   tokens = (const int*)d_in[0];
  const float* emb    = (const float*)d_in[1];
  const float* Wx     = (const float*)d_in[2];
  const float* Wh     = (const float*)d_in[3];
  const float* brnn   = (const float*)d_in[4];
  const float* W1     = (const float*)d_in[5];
  const float* b1     = (const float*)d_in[6];
  const float* W2     = (const float*)d_in[7];
  const float* b2     = (const float*)d_in[8];
  const float* Wo     = (const float*)d_in[9];
  const float* bo     = (const float*)d_in[10];
  float* out = (float*)d_out;

  char* ws = (char*)d_ws;
  size_t off = 0;
  auto alloc = [&](size_t bytes) -> void* {
    void* p = ws + off;
    off += (bytes + 255) & ~(size_t)255;
    return p;
  };
  u16* WxT    = (u16*)alloc((size_t)512 * 512 * 2);     // Wx transposed, bf16
  u16* xproj  = (u16*)alloc((size_t)32768 * 512 * 2);   // SH4*(x@Wx + b), f16
  uint4* Wf4  = (uint4*)alloc((size_t)128 * 64 * 16);   // Wh fp4 B-fragments
  unsigned char* masks8 = (unsigned char*)alloc(32768); // token!=0 bytes
  u32* W1p    = (u32*)alloc((size_t)256 * 1024 * 4);
  u32* W2p    = (u32*)alloc((size_t)512 * 1024 * 4);
  u32* Wop    = (u32*)alloc((size_t)512 * 1000 * 4);
  u32* hpack  = (u32*)alloc((size_t)64 * 256 * 4);

  k_trans_cvt<<<dim3(64), dim3(256), 0, stream>>>(Wx, WxT);
  k_prep_w4<<<dim3(32), dim3(256), 0, stream>>>(Wh, Wf4);
  k_mask<<<dim3(128), dim3(256), 0, stream>>>(tokens, masks8);
  k_pack_pairs<<<dim3(4, 256), dim3(256), 0, stream>>>(W1, W1p, 1024);
  k_pack_pairs<<<dim3(4, 512), dim3(256), 0, stream>>>(W2, W2p, 1024);
  k_pack_pairs<<<dim3(4, 512), dim3(256), 0, stream>>>(Wo, Wop, 1000);
  k_gemm<<<dim3(256, 4), dim3(256), 0, stream>>>(tokens, emb, WxT, brnn, xproj);
  k_rnn<<<dim3(64), dim3(512), 0, stream>>>(Wf4, xproj, masks8, hpack);
  k_tail<<<dim3(64), dim3(256), 0, stream>>>(hpack, W1p, b1, W2p, b2, Wop, bo, out);
}